// Round 6
// baseline (483.735 us; speedup 1.0000x reference)
//
#include <hip/hip_runtime.h>
#include <hip/hip_bf16.h>

constexpr int MTOK = 1024;   // B*S
constexpr int HDIM = 2048;
constexpr int IDIM = 2048;
constexpr int NEXP = 16;
constexpr int TOPK = 4;
constexpr int NA   = MTOK * TOPK;   // 4096 assignments

#define ALPHA_C 1.702f
#define LIMIT_C 7.0f
#define RMS_EPS 1e-5f

using short8   = __attribute__((ext_vector_type(8))) short;
using f32x4    = __attribute__((ext_vector_type(4))) float;

__device__ __forceinline__ unsigned short f2bf(float f) {
    unsigned u = __builtin_bit_cast(unsigned, f);
    u += 0x7fffu + ((u >> 16) & 1u);     // round-to-nearest-even
    return (unsigned short)(u >> 16);
}

__device__ __forceinline__ unsigned pack2bf(float lo, float hi) {
    return (unsigned)f2bf(lo) | ((unsigned)f2bf(hi) << 16);
}

// pack 8 f32 -> 8 bf16 (RNE)
__device__ __forceinline__ short8 cvt8(const float4 a, const float4 b) {
    union { short8 s; unsigned u[4]; } r;
    r.u[0] = pack2bf(a.x, a.y);
    r.u[1] = pack2bf(a.z, a.w);
    r.u[2] = pack2bf(b.x, b.y);
    r.u[3] = pack2bf(b.z, b.w);
    return r.s;
}

// ---------------- out = x ----------------
__global__ void k_copy(const float* __restrict__ x, float* __restrict__ out, int n4) {
    int i = blockIdx.x * blockDim.x + threadIdx.x;
    int stride = gridDim.x * blockDim.x;
    const float4* xs = (const float4*)x;
    float4* os = (float4*)out;
    for (; i < n4; i += stride) os[i] = xs[i];
}

// ---------------- RMSNorm + router + top-k ----------------
__global__ __launch_bounds__(256) void k_router(
    const float* __restrict__ x, const float* __restrict__ norm_w,
    const float* __restrict__ gate_w, const float* __restrict__ gate_b,
    unsigned short* __restrict__ t_bf,
    int* __restrict__ counts, int* __restrict__ idx_of,
    int* __restrict__ slot_of, float* __restrict__ gate_mk)
{
    __shared__ float t_lds[HDIM];
    __shared__ float red[4];
    __shared__ float logits[NEXP];

    const int m   = blockIdx.x;
    const int tid = threadIdx.x;
    const float* xr = x + (size_t)m * HDIM;

    float4 v0 = ((const float4*)xr)[tid * 2];
    float4 v1 = ((const float4*)xr)[tid * 2 + 1];
    float ss = v0.x*v0.x + v0.y*v0.y + v0.z*v0.z + v0.w*v0.w
             + v1.x*v1.x + v1.y*v1.y + v1.z*v1.z + v1.w*v1.w;
    #pragma unroll
    for (int off = 32; off > 0; off >>= 1) ss += __shfl_down(ss, off);
    if ((tid & 63) == 0) red[tid >> 6] = ss;
    __syncthreads();
    float tot = red[0] + red[1] + red[2] + red[3];
    float scale = rsqrtf(tot / (float)HDIM + RMS_EPS);

    float4 n0 = ((const float4*)norm_w)[tid * 2];
    float4 n1 = ((const float4*)norm_w)[tid * 2 + 1];
    float t[8];
    t[0]=v0.x*scale*n0.x; t[1]=v0.y*scale*n0.y; t[2]=v0.z*scale*n0.z; t[3]=v0.w*scale*n0.w;
    t[4]=v1.x*scale*n1.x; t[5]=v1.y*scale*n1.y; t[6]=v1.z*scale*n1.z; t[7]=v1.w*scale*n1.w;
    short8 pk;
    #pragma unroll
    for (int j = 0; j < 8; ++j) {
        t_lds[tid * 8 + j] = t[j];
        pk[j] = (short)f2bf(t[j]);
    }
    *(short8*)(t_bf + (size_t)m * HDIM + tid * 8) = pk;
    __syncthreads();

    const int e = tid >> 4, j = tid & 15;
    const float4* gw4 = (const float4*)(gate_w + (size_t)e * HDIM);
    const float4* tl4 = (const float4*)t_lds;
    float part = 0.f;
    for (int h4 = j; h4 < HDIM / 4; h4 += 16) {
        float4 g = gw4[h4], tv = tl4[h4];
        part += g.x*tv.x + g.y*tv.y + g.z*tv.z + g.w*tv.w;
    }
    #pragma unroll
    for (int off = 8; off > 0; off >>= 1) part += __shfl_xor(part, off);
    if (j == 0) logits[e] = part + gate_b[e];
    __syncthreads();

    if (tid == 0) {
        float lv[NEXP];
        #pragma unroll
        for (int q = 0; q < NEXP; ++q) lv[q] = logits[q];
        int   sel[TOPK];
        float sv[TOPK];
        #pragma unroll
        for (int k = 0; k < TOPK; ++k) {
            float best = -1e30f; int bi = 0;
            for (int q = 0; q < NEXP; ++q)
                if (lv[q] > best) { best = lv[q]; bi = q; }
            sel[k] = bi; sv[k] = best; lv[bi] = -1e30f;
        }
        float mx = sv[0], s = 0.f, g[TOPK];
        #pragma unroll
        for (int k = 0; k < TOPK; ++k) { g[k] = __expf(sv[k] - mx); s += g[k]; }
        float inv = 1.f / s;
        #pragma unroll
        for (int k = 0; k < TOPK; ++k) {
            int a = m * TOPK + k;
            int slot = atomicAdd(&counts[sel[k]], 1);
            idx_of[a]  = sel[k];
            slot_of[a] = slot;
            gate_mk[a] = g[k] * inv;
        }
    }
}

__global__ void k_offsets(const int* __restrict__ counts, int* __restrict__ offsets) {
    if (threadIdx.x == 0) {
        int s = 0;
        for (int e = 0; e < NEXP; ++e) { offsets[e] = s; s += counts[e]; }
        offsets[NEXP] = s;
    }
}

__global__ void k_remap(const int* __restrict__ idx_of, const int* __restrict__ slot_of,
                        const float* __restrict__ gate_mk, const int* __restrict__ offsets,
                        int* __restrict__ token_of, float* __restrict__ gate_row)
{
    int a = blockIdx.x * blockDim.x + threadIdx.x;
    if (a >= NA) return;
    int e = idx_of[a];
    int r = offsets[e] + slot_of[a];
    token_of[r] = a >> 2;
    gate_row[r] = gate_mk[a];
}

// ---------------- GEMM1 + bias + clamped SwiGLU -> act (bf16) ----------------
// BM=320, 4 waves; wave wv owns rows [wv*80, wv*80+80) x 64 o-cols.
// A fragments load DIRECT global->register (waves own disjoint rows; the
// 16x16x32 A-frag is a 16-row x 64B gather). Only B goes through LDS
// (fp32->bf16 cvt), double-buffered, lgkmcnt-only barriers, depth-2 prefetch.
__global__ __launch_bounds__(256) void k_gemm1(
    const unsigned short* __restrict__ t_bf,
    const float* __restrict__ w1, const float* __restrict__ b1,
    const int* __restrict__ counts, const int* __restrict__ offsets,
    const int* __restrict__ token_of,
    unsigned short* __restrict__ act)
{
    __shared__ unsigned char lB[2][5120];   // [64 cols][80 B]

    const int e  = blockIdx.z;
    const int ne = counts[e];
    const int brow = blockIdx.y * 320;
    if (brow >= ne) return;
    const int roff = offsets[e];
    const int i0 = blockIdx.x * 32;
    const int tid = threadIdx.x;

    const int wv = tid >> 6, ln = tid & 63;
    const int lr = ln & 15, lk = ln >> 4;
    const int br = tid >> 2, bp = tid & 3;   // B staging: col row br, 16B chunk bp

    // per-mf A fragment base: row = brow + wv*80 + mf*16 + lr, k-offset lk*8
    const unsigned short* aptr[5];
    #pragma unroll
    for (int mf = 0; mf < 5; ++mf) {
        int rg = brow + wv * 80 + mf * 16 + lr;
        int tok = token_of[roff + (rg < ne ? rg : 0)];
        aptr[mf] = t_bf + (size_t)tok * HDIM + lk * 8;
    }
    const int o = (br < 32) ? (2 * (i0 + br)) : (2 * (i0 + br - 32) + 1);
    const float* bsrc = w1 + ((size_t)e * (2 * IDIM) + o) * HDIM + bp * 8;

    short8 afrE[5], afrO[5];
    float4 bR0, bR1;
    f32x4 acc[5][4] = {};

    // prologue: A frags t0/t1, B t0 published, B t1 in regs
    #pragma unroll
    for (int mf = 0; mf < 5; ++mf) afrE[mf] = *(const short8*)(aptr[mf]);
    bR0 = *(const float4*)(bsrc);
    bR1 = *(const float4*)(bsrc + 4);
    *(short8*)(&lB[0][br * 80 + bp * 16]) = cvt8(bR0, bR1);
    #pragma unroll
    for (int mf = 0; mf < 5; ++mf) afrO[mf] = *(const short8*)(aptr[mf] + 32);
    bR0 = *(const float4*)(bsrc + 32);
    bR1 = *(const float4*)(bsrc + 32 + 4);
    asm volatile("s_waitcnt lgkmcnt(0)" ::: "memory");
    __builtin_amdgcn_s_barrier();

    for (int tp = 0; tp < 32; ++tp) {
        // ---- even step t = 2*tp, consume lB[0] / afrE ----
        {
            const int t = 2 * tp;
            *(short8*)(&lB[1][br * 80 + bp * 16]) = cvt8(bR0, bR1);   // publish t+1
            if (t + 2 < 64) {
                bR0 = *(const float4*)(bsrc + (t + 2) * 32);
                bR1 = *(const float4*)(bsrc + (t + 2) * 32 + 4);
            }
            short8 bfr[4];
            #pragma unroll
            for (int n = 0; n < 4; ++n)
                bfr[n] = *(const short8*)(&lB[0][(n * 16 + lr) * 80 + lk * 16]);
            #pragma unroll
            for (int mf = 0; mf < 5; ++mf)
                #pragma unroll
                for (int n = 0; n < 4; ++n)
                    acc[mf][n] = __builtin_amdgcn_mfma_f32_16x16x32_bf16(afrE[mf], bfr[n], acc[mf][n], 0, 0, 0);
            if (t + 2 < 64) {
                #pragma unroll
                for (int mf = 0; mf < 5; ++mf)
                    afrE[mf] = *(const short8*)(aptr[mf] + (t + 2) * 32);
            }
            asm volatile("s_waitcnt lgkmcnt(0)" ::: "memory");
            __builtin_amdgcn_s_barrier();
        }
        // ---- odd step t = 2*tp+1, consume lB[1] / afrO ----
        {
            const int t = 2 * tp + 1;
            if (t + 1 < 64)
                *(short8*)(&lB[0][br * 80 + bp * 16]) = cvt8(bR0, bR1);   // publish t+1
            if (t + 2 < 64) {
                bR0 = *(const float4*)(bsrc + (t + 2) * 32);
                bR1 = *(const float4*)(bsrc + (t + 2) * 32 + 4);
            }
            short8 bfr[4];
            #pragma unroll
            for (int n = 0; n < 4; ++n)
                bfr[n] = *(const short8*)(&lB[1][(n * 16 + lr) * 80 + lk * 16]);
            #pragma unroll
            for (int mf = 0; mf < 5; ++mf)
                #pragma unroll
                for (int n = 0; n < 4; ++n)
                    acc[mf][n] = __builtin_amdgcn_mfma_f32_16x16x32_bf16(afrO[mf], bfr[n], acc[mf][n], 0, 0, 0);
            if (t + 2 < 64) {
                #pragma unroll
                for (int mf = 0; mf < 5; ++mf)
                    afrO[mf] = *(const short8*)(aptr[mf] + (t + 2) * 32);
            }
            asm volatile("s_waitcnt lgkmcnt(0)" ::: "memory");
            __builtin_amdgcn_s_barrier();
        }
    }

    #pragma unroll
    for (int n = 0; n < 2; ++n) {
        const int i = i0 + n * 16 + lr;
        const float ba = b1[(size_t)e * (2 * IDIM) + 2 * i];
        const float bb = b1[(size_t)e * (2 * IDIM) + 2 * i + 1];
        #pragma unroll
        for (int mf = 0; mf < 5; ++mf) {
            #pragma unroll
            for (int r = 0; r < 4; ++r) {
                const int rg = brow + wv * 80 + mf * 16 + lk * 4 + r;
                if (rg < ne) {
                    float ha = acc[mf][n][r] + ba;
                    float hb = acc[mf][n + 2][r] + bb;
                    float a = fminf(ha, LIMIT_C);
                    float b = fminf(fmaxf(hb, -LIMIT_C), LIMIT_C);
                    float s = 1.f / (1.f + __expf(-ALPHA_C * a));
                    act[(size_t)(roff + rg) * IDIM + i] = f2bf(a * s * (b + 1.f));
                }
            }
        }
    }
}

// ---------------- GEMM2 + bias, gate-scale, atomic combine ----------------
__global__ __launch_bounds__(256) void k_gemm2(
    const unsigned short* __restrict__ act,
    const float* __restrict__ w2, const float* __restrict__ b2,
    const int* __restrict__ counts, const int* __restrict__ offsets,
    const int* __restrict__ token_of, const float* __restrict__ gate_row,
    float* __restrict__ out)
{
    __shared__ unsigned char lB[2][5120];

    const int e  = blockIdx.z;
    const int ne = counts[e];
    const int brow = blockIdx.y * 320;
    if (brow >= ne) return;
    const int roff = offsets[e];
    const int ks = blockIdx.x & 1;
    const int d0 = (blockIdx.x >> 1) * 64;
    const int kbeg = ks * (IDIM / 2);
    const int tid = threadIdx.x;

    const int wv = tid >> 6, ln = tid & 63;
    const int lr = ln & 15, lk = ln >> 4;
    const int br = tid >> 2, bp = tid & 3;

    const unsigned short* aptr[5];
    #pragma unroll
    for (int mf = 0; mf < 5; ++mf) {
        int rg = brow + wv * 80 + mf * 16 + lr;
        int rc = (rg < ne) ? rg : 0;
        aptr[mf] = act + (size_t)(roff + rc) * IDIM + kbeg + lk * 8;
    }
    const float* bsrc = w2 + ((size_t)e * HDIM + d0 + br) * IDIM + kbeg + bp * 8;

    short8 afrE[5], afrO[5];
    float4 bR0, bR1;
    f32x4 acc[5][4] = {};

    #pragma unroll
    for (int mf = 0; mf < 5; ++mf) afrE[mf] = *(const short8*)(aptr[mf]);
    bR0 = *(const float4*)(bsrc);
    bR1 = *(const float4*)(bsrc + 4);
    *(short8*)(&lB[0][br * 80 + bp * 16]) = cvt8(bR0, bR1);
    #pragma unroll
    for (int mf = 0; mf < 5; ++mf) afrO[mf] = *(const short8*)(aptr[mf] + 32);
    bR0 = *(const float4*)(bsrc + 32);
    bR1 = *(const float4*)(bsrc + 32 + 4);
    asm volatile("s_waitcnt lgkmcnt(0)" ::: "memory");
    __builtin_amdgcn_s_barrier();

    for (int tp = 0; tp < 16; ++tp) {
        {
            const int t = 2 * tp;
            *(short8*)(&lB[1][br * 80 + bp * 16]) = cvt8(bR0, bR1);
            if (t + 2 < 32) {
                bR0 = *(const float4*)(bsrc + (t + 2) * 32);
                bR1 = *(const float4*)(bsrc + (t + 2) * 32 + 4);
            }
            short8 bfr[4];
            #pragma unroll
            for (int n = 0; n < 4; ++n)
                bfr[n] = *(const short8*)(&lB[0][(n * 16 + lr) * 80 + lk * 16]);
            #pragma unroll
            for (int mf = 0; mf < 5; ++mf)
                #pragma unroll
                for (int n = 0; n < 4; ++n)
                    acc[mf][n] = __builtin_amdgcn_mfma_f32_16x16x32_bf16(afrE[mf], bfr[n], acc[mf][n], 0, 0, 0);
            if (t + 2 < 32) {
                #pragma unroll
                for (int mf = 0; mf < 5; ++mf)
                    afrE[mf] = *(const short8*)(aptr[mf] + (t + 2) * 32);
            }
            asm volatile("s_waitcnt lgkmcnt(0)" ::: "memory");
            __builtin_amdgcn_s_barrier();
        }
        {
            const int t = 2 * tp + 1;
            if (t + 1 < 32)
                *(short8*)(&lB[0][br * 80 + bp * 16]) = cvt8(bR0, bR1);
            if (t + 2 < 32) {
                bR0 = *(const float4*)(bsrc + (t + 2) * 32);
                bR1 = *(const float4*)(bsrc + (t + 2) * 32 + 4);
            }
            short8 bfr[4];
            #pragma unroll
            for (int n = 0; n < 4; ++n)
                bfr[n] = *(const short8*)(&lB[1][(n * 16 + lr) * 80 + lk * 16]);
            #pragma unroll
            for (int mf = 0; mf < 5; ++mf)
                #pragma unroll
                for (int n = 0; n < 4; ++n)
                    acc[mf][n] = __builtin_amdgcn_mfma_f32_16x16x32_bf16(afrO[mf], bfr[n], acc[mf][n], 0, 0, 0);
            if (t + 2 < 32) {
                #pragma unroll
                for (int mf = 0; mf < 5; ++mf)
                    afrO[mf] = *(const short8*)(aptr[mf] + (t + 2) * 32);
            }
            asm volatile("s_waitcnt lgkmcnt(0)" ::: "memory");
            __builtin_amdgcn_s_barrier();
        }
    }

    #pragma unroll
    for (int mf = 0; mf < 5; ++mf) {
        #pragma unroll
        for (int r = 0; r < 4; ++r) {
            const int rg = brow + wv * 80 + mf * 16 + lk * 4 + r;
            if (rg >= ne) continue;
            const int tok = token_of[roff + rg];
            const float g = gate_row[roff + rg];
            float* orow = out + (size_t)tok * HDIM;
            #pragma unroll
            for (int n = 0; n < 4; ++n) {
                const int d = d0 + n * 16 + lr;
                float v = g * acc[mf][n][r];
                if (ks == 0) v += g * b2[(size_t)e * HDIM + d];
                atomicAdd(orow + d, v);
            }
        }
    }
}

extern "C" void kernel_launch(void* const* d_in, const int* in_sizes, int n_in,
                              void* d_out, int out_size, void* d_ws, size_t ws_size,
                              hipStream_t stream) {
    const float* x      = (const float*)d_in[0];
    const float* norm_w = (const float*)d_in[1];
    const float* gate_w = (const float*)d_in[2];
    const float* gate_b = (const float*)d_in[3];
    const float* w1     = (const float*)d_in[4];
    const float* b1     = (const float*)d_in[5];
    const float* w2     = (const float*)d_in[6];
    const float* b2     = (const float*)d_in[7];
    float* out = (float*)d_out;

    char* ws = (char*)d_ws;
    size_t off = 0;
    unsigned short* t_bf = (unsigned short*)(ws + off); off += (size_t)MTOK * HDIM * 2;  // 4 MB
    unsigned short* actb = (unsigned short*)(ws + off); off += (size_t)NA * IDIM * 2;    // 16.8 MB
    int*   counts   = (int*)(ws + off);   off += 256;
    int*   offsets  = (int*)(ws + off);   off += 256;
    int*   idx_of   = (int*)(ws + off);   off += (size_t)NA * 4;
    int*   slot_of  = (int*)(ws + off);   off += (size_t)NA * 4;
    float* gate_mk  = (float*)(ws + off); off += (size_t)NA * 4;
    int*   token_of = (int*)(ws + off);   off += (size_t)NA * 4;
    float* gate_row = (float*)(ws + off); off += (size_t)NA * 4;

    (void)hipMemsetAsync(counts, 0, 256, stream);
    k_copy<<<1024, 256, 0, stream>>>(x, out, MTOK * HDIM / 4);
    k_router<<<MTOK, 256, 0, stream>>>(x, norm_w, gate_w, gate_b, t_bf,
                                       counts, idx_of, slot_of, gate_mk);
    k_offsets<<<1, 64, 0, stream>>>(counts, offsets);
    k_remap<<<NA / 256, 256, 0, stream>>>(idx_of, slot_of, gate_mk, offsets,
                                          token_of, gate_row);
    k_gemm1<<<dim3(IDIM / 32, (MTOK + 319) / 320, NEXP), 256, 0, stream>>>(
        t_bf, w1, b1, counts, offsets, token_of, actb);
    k_gemm2<<<dim3((HDIM / 64) * 2, (MTOK + 319) / 320, NEXP), 256, 0, stream>>>(
        actb, w2, b2, counts, offsets, token_of, gate_row, out);
}

// Round 7
// 481.187 us; speedup vs baseline: 1.0053x; 1.0053x over previous
//
#include <hip/hip_runtime.h>
#include <hip/hip_bf16.h>

constexpr int MTOK = 1024;   // B*S
constexpr int HDIM = 2048;
constexpr int IDIM = 2048;
constexpr int NEXP = 16;
constexpr int TOPK = 4;
constexpr int NA   = MTOK * TOPK;   // 4096 assignments

#define ALPHA_C 1.702f
#define LIMIT_C 7.0f
#define RMS_EPS 1e-5f

using short8 = __attribute__((ext_vector_type(8))) short;
using f32x4  = __attribute__((ext_vector_type(4))) float;

__device__ __forceinline__ unsigned short f2bf(float f) {
    unsigned u = __builtin_bit_cast(unsigned, f);
    u += 0x7fffu + ((u >> 16) & 1u);     // round-to-nearest-even
    return (unsigned short)(u >> 16);
}

__device__ __forceinline__ unsigned pack2bf(float lo, float hi) {
    return (unsigned)f2bf(lo) | ((unsigned)f2bf(hi) << 16);
}

// pack 8 f32 -> 8 bf16 (RNE)
__device__ __forceinline__ short8 cvt8(const float4 a, const float4 b) {
    union { short8 s; unsigned u[4]; } r;
    r.u[0] = pack2bf(a.x, a.y);
    r.u[1] = pack2bf(a.z, a.w);
    r.u[2] = pack2bf(b.x, b.y);
    r.u[3] = pack2bf(b.z, b.w);
    return r.s;
}

// ---------------- RMSNorm + router + top-k (+ out = x fused) ----------------
__global__ __launch_bounds__(256) void k_router(
    const float* __restrict__ x, const float* __restrict__ norm_w,
    const float* __restrict__ gate_w, const float* __restrict__ gate_b,
    float* __restrict__ out,
    unsigned short* __restrict__ t_bf,
    int* __restrict__ counts, int* __restrict__ idx_of,
    int* __restrict__ slot_of, float* __restrict__ gate_mk)
{
    __shared__ float t_lds[HDIM];
    __shared__ float red[4];
    __shared__ float logits[NEXP];

    const int m   = blockIdx.x;
    const int tid = threadIdx.x;
    const float* xr = x + (size_t)m * HDIM;

    float4 v0 = ((const float4*)xr)[tid * 2];
    float4 v1 = ((const float4*)xr)[tid * 2 + 1];
    // fused residual copy: out = x
    ((float4*)(out + (size_t)m * HDIM))[tid * 2]     = v0;
    ((float4*)(out + (size_t)m * HDIM))[tid * 2 + 1] = v1;

    float ss = v0.x*v0.x + v0.y*v0.y + v0.z*v0.z + v0.w*v0.w
             + v1.x*v1.x + v1.y*v1.y + v1.z*v1.z + v1.w*v1.w;
    #pragma unroll
    for (int off = 32; off > 0; off >>= 1) ss += __shfl_down(ss, off);
    if ((tid & 63) == 0) red[tid >> 6] = ss;
    __syncthreads();
    float tot = red[0] + red[1] + red[2] + red[3];
    float scale = rsqrtf(tot / (float)HDIM + RMS_EPS);

    float4 n0 = ((const float4*)norm_w)[tid * 2];
    float4 n1 = ((const float4*)norm_w)[tid * 2 + 1];
    float t[8];
    t[0]=v0.x*scale*n0.x; t[1]=v0.y*scale*n0.y; t[2]=v0.z*scale*n0.z; t[3]=v0.w*scale*n0.w;
    t[4]=v1.x*scale*n1.x; t[5]=v1.y*scale*n1.y; t[6]=v1.z*scale*n1.z; t[7]=v1.w*scale*n1.w;
    short8 pk;
    #pragma unroll
    for (int j = 0; j < 8; ++j) {
        t_lds[tid * 8 + j] = t[j];
        pk[j] = (short)f2bf(t[j]);
    }
    *(short8*)(t_bf + (size_t)m * HDIM + tid * 8) = pk;
    __syncthreads();

    const int e = tid >> 4, j = tid & 15;
    const float4* gw4 = (const float4*)(gate_w + (size_t)e * HDIM);
    const float4* tl4 = (const float4*)t_lds;
    float part = 0.f;
    for (int h4 = j; h4 < HDIM / 4; h4 += 16) {
        float4 g = gw4[h4], tv = tl4[h4];
        part += g.x*tv.x + g.y*tv.y + g.z*tv.z + g.w*tv.w;
    }
    #pragma unroll
    for (int off = 8; off > 0; off >>= 1) part += __shfl_xor(part, off);
    if (j == 0) logits[e] = part + gate_b[e];
    __syncthreads();

    if (tid == 0) {
        float lv[NEXP];
        #pragma unroll
        for (int q = 0; q < NEXP; ++q) lv[q] = logits[q];
        int   sel[TOPK];
        float sv[TOPK];
        #pragma unroll
        for (int k = 0; k < TOPK; ++k) {
            float best = -1e30f; int bi = 0;
            for (int q = 0; q < NEXP; ++q)
                if (lv[q] > best) { best = lv[q]; bi = q; }
            sel[k] = bi; sv[k] = best; lv[bi] = -1e30f;
        }
        float mx = sv[0], s = 0.f, g[TOPK];
        #pragma unroll
        for (int k = 0; k < TOPK; ++k) { g[k] = __expf(sv[k] - mx); s += g[k]; }
        float inv = 1.f / s;
        #pragma unroll
        for (int k = 0; k < TOPK; ++k) {
            int a = m * TOPK + k;
            int slot = atomicAdd(&counts[sel[k]], 1);
            idx_of[a]  = sel[k];
            slot_of[a] = slot;
            gate_mk[a] = g[k] * inv;
        }
    }
}

// ---------------- scatter tokens into compact per-expert rows ----------------
__global__ void k_remap(const int* __restrict__ idx_of, const int* __restrict__ slot_of,
                        const float* __restrict__ gate_mk, const int* __restrict__ counts,
                        int* __restrict__ token_of, float* __restrict__ gate_row)
{
    int a = blockIdx.x * blockDim.x + threadIdx.x;
    if (a >= NA) return;
    int e = idx_of[a];
    int off = 0;
    for (int q = 0; q < NEXP; ++q) off += (q < e) ? counts[q] : 0;
    int r = off + slot_of[a];
    token_of[r] = a >> 2;
    gate_row[r] = gate_mk[a];
}

// ---------------- GEMM1 + bias + clamped SwiGLU -> act (bf16) ----------------
// BM=320, 4 waves; wave wv owns rows [wv*80, wv*80+80) x 64 o-cols.
// A fragments: direct global->reg, depth-2. B: 4 named reg sets (depth-4,
// 3-step latency budget) -> cvt -> LDS double-buffer. One raw s_barrier +
// lgkmcnt(0) per K-step; vmem stays in flight across barriers.
__global__ __launch_bounds__(256) void k_gemm1(
    const unsigned short* __restrict__ t_bf,
    const float* __restrict__ w1, const float* __restrict__ b1,
    const int* __restrict__ counts, const int* __restrict__ token_of,
    unsigned short* __restrict__ act)
{
    __shared__ unsigned char lB[2][5120];   // [64 cols][80 B]

    const int e = blockIdx.z;
    int ne = 0, roff = 0;
    #pragma unroll
    for (int q = 0; q < NEXP; ++q) {
        int cq = counts[q];
        roff += (q < e) ? cq : 0;
        ne    = (q == e) ? cq : ne;
    }
    const int brow = blockIdx.y * 320;
    if (brow >= ne) return;
    const int i0 = blockIdx.x * 32;
    const int tid = threadIdx.x;

    const int wv = tid >> 6, ln = tid & 63;
    const int lr = ln & 15, lk = ln >> 4;
    const int br = tid >> 2, bp = tid & 3;

    const unsigned short* aptr[5];
    #pragma unroll
    for (int mf = 0; mf < 5; ++mf) {
        int rg = brow + wv * 80 + mf * 16 + lr;
        int tok = token_of[roff + (rg < ne ? rg : 0)];
        aptr[mf] = t_bf + (size_t)tok * HDIM + lk * 8;
    }
    const int o = (br < 32) ? (2 * (i0 + br)) : (2 * (i0 + br - 32) + 1);
    const float* bsrc = w1 + ((size_t)e * (2 * IDIM) + o) * HDIM + bp * 8;

    short8 aS[2][5];
    float4 bS[4][2];
    f32x4  acc[5][4] = {};

    // prologue: publish tile0, stage tiles 1..3 in regs, A tiles 0,1
    {
        float4 p0 = *(const float4*)(bsrc);
        float4 p1 = *(const float4*)(bsrc + 4);
        *(short8*)(&lB[0][br * 80 + bp * 16]) = cvt8(p0, p1);
    }
    bS[1][0] = *(const float4*)(bsrc + 32);  bS[1][1] = *(const float4*)(bsrc + 36);
    bS[2][0] = *(const float4*)(bsrc + 64);  bS[2][1] = *(const float4*)(bsrc + 68);
    bS[3][0] = *(const float4*)(bsrc + 96);  bS[3][1] = *(const float4*)(bsrc + 100);
    #pragma unroll
    for (int mf = 0; mf < 5; ++mf) {
        aS[0][mf] = *(const short8*)(aptr[mf]);
        aS[1][mf] = *(const short8*)(aptr[mf] + 32);
    }
    asm volatile("s_waitcnt lgkmcnt(0)" ::: "memory");
    __builtin_amdgcn_s_barrier();

#define GSTEP(T, P)                                                                          \
    {                                                                                        \
        const int t_ = (T);                                                                  \
        if (t_ + 1 < 64)                                                                     \
            *(short8*)(&lB[((P) & 1) ^ 1][br * 80 + bp * 16]) =                              \
                cvt8(bS[((P) + 1) & 3][0], bS[((P) + 1) & 3][1]);                            \
        if (t_ + 4 < 64) {                                                                   \
            bS[(P)][0] = *(const float4*)(bsrc + (t_ + 4) * 32);                             \
            bS[(P)][1] = *(const float4*)(bsrc + (t_ + 4) * 32 + 4);                         \
        }                                                                                    \
        short8 bfr[4];                                                                       \
        _Pragma("unroll")                                                                    \
        for (int n = 0; n < 4; ++n)                                                          \
            bfr[n] = *(const short8*)(&lB[(P) & 1][(n * 16 + lr) * 80 + lk * 16]);           \
        _Pragma("unroll")                                                                    \
        for (int mf = 0; mf < 5; ++mf)                                                       \
            _Pragma("unroll")                                                                \
            for (int n = 0; n < 4; ++n)                                                      \
                acc[mf][n] = __builtin_amdgcn_mfma_f32_16x16x32_bf16(                        \
                    aS[(P) & 1][mf], bfr[n], acc[mf][n], 0, 0, 0);                           \
        if (t_ + 2 < 64) {                                                                   \
            _Pragma("unroll")                                                                \
            for (int mf = 0; mf < 5; ++mf)                                                   \
                aS[(P) & 1][mf] = *(const short8*)(aptr[mf] + (t_ + 2) * 32);                \
        }                                                                                    \
        asm volatile("s_waitcnt lgkmcnt(0)" ::: "memory");                                   \
        __builtin_amdgcn_s_barrier();                                                        \
    }

    for (int t16 = 0; t16 < 16; ++t16) {
        const int tb = t16 * 4;
        GSTEP(tb + 0, 0)
        GSTEP(tb + 1, 1)
        GSTEP(tb + 2, 2)
        GSTEP(tb + 3, 3)
    }
#undef GSTEP

    #pragma unroll
    for (int n = 0; n < 2; ++n) {
        const int i = i0 + n * 16 + lr;
        const float ba = b1[(size_t)e * (2 * IDIM) + 2 * i];
        const float bb = b1[(size_t)e * (2 * IDIM) + 2 * i + 1];
        #pragma unroll
        for (int mf = 0; mf < 5; ++mf) {
            #pragma unroll
            for (int r = 0; r < 4; ++r) {
                const int rg = brow + wv * 80 + mf * 16 + lk * 4 + r;
                if (rg < ne) {
                    float ha = acc[mf][n][r] + ba;
                    float hb = acc[mf][n + 2][r] + bb;
                    float a = fminf(ha, LIMIT_C);
                    float b = fminf(fmaxf(hb, -LIMIT_C), LIMIT_C);
                    float s = 1.f / (1.f + __expf(-ALPHA_C * a));
                    act[(size_t)(roff + rg) * IDIM + i] = f2bf(a * s * (b + 1.f));
                }
            }
        }
    }
}

// ---------------- GEMM2 + bias, gate-scale, atomic combine ----------------
__global__ __launch_bounds__(256) void k_gemm2(
    const unsigned short* __restrict__ act,
    const float* __restrict__ w2, const float* __restrict__ b2,
    const int* __restrict__ counts, const int* __restrict__ token_of,
    const float* __restrict__ gate_row,
    float* __restrict__ out)
{
    __shared__ unsigned char lB[2][5120];

    const int e = blockIdx.z;
    int ne = 0, roff = 0;
    #pragma unroll
    for (int q = 0; q < NEXP; ++q) {
        int cq = counts[q];
        roff += (q < e) ? cq : 0;
        ne    = (q == e) ? cq : ne;
    }
    const int brow = blockIdx.y * 320;
    if (brow >= ne) return;
    const int ks = blockIdx.x & 1;
    const int d0 = (blockIdx.x >> 1) * 64;
    const int kbeg = ks * (IDIM / 2);
    const int tid = threadIdx.x;

    const int wv = tid >> 6, ln = tid & 63;
    const int lr = ln & 15, lk = ln >> 4;
    const int br = tid >> 2, bp = tid & 3;

    const unsigned short* aptr[5];
    #pragma unroll
    for (int mf = 0; mf < 5; ++mf) {
        int rg = brow + wv * 80 + mf * 16 + lr;
        int rc = (rg < ne) ? rg : 0;
        aptr[mf] = act + (size_t)(roff + rc) * IDIM + kbeg + lk * 8;
    }
    const float* bsrc = w2 + ((size_t)e * HDIM + d0 + br) * IDIM + kbeg + bp * 8;

    short8 aS[2][5];
    float4 bS[4][2];
    f32x4  acc[5][4] = {};

    {
        float4 p0 = *(const float4*)(bsrc);
        float4 p1 = *(const float4*)(bsrc + 4);
        *(short8*)(&lB[0][br * 80 + bp * 16]) = cvt8(p0, p1);
    }
    bS[1][0] = *(const float4*)(bsrc + 32);  bS[1][1] = *(const float4*)(bsrc + 36);
    bS[2][0] = *(const float4*)(bsrc + 64);  bS[2][1] = *(const float4*)(bsrc + 68);
    bS[3][0] = *(const float4*)(bsrc + 96);  bS[3][1] = *(const float4*)(bsrc + 100);
    #pragma unroll
    for (int mf = 0; mf < 5; ++mf) {
        aS[0][mf] = *(const short8*)(aptr[mf]);
        aS[1][mf] = *(const short8*)(aptr[mf] + 32);
    }
    asm volatile("s_waitcnt lgkmcnt(0)" ::: "memory");
    __builtin_amdgcn_s_barrier();

#define GSTEP(T, P)                                                                          \
    {                                                                                        \
        const int t_ = (T);                                                                  \
        if (t_ + 1 < 32)                                                                     \
            *(short8*)(&lB[((P) & 1) ^ 1][br * 80 + bp * 16]) =                              \
                cvt8(bS[((P) + 1) & 3][0], bS[((P) + 1) & 3][1]);                            \
        if (t_ + 4 < 32) {                                                                   \
            bS[(P)][0] = *(const float4*)(bsrc + (t_ + 4) * 32);                             \
            bS[(P)][1] = *(const float4*)(bsrc + (t_ + 4) * 32 + 4);                         \
        }                                                                                    \
        short8 bfr[4];                                                                       \
        _Pragma("unroll")                                                                    \
        for (int n = 0; n < 4; ++n)                                                          \
            bfr[n] = *(const short8*)(&lB[(P) & 1][(n * 16 + lr) * 80 + lk * 16]);           \
        _Pragma("unroll")                                                                    \
        for (int mf = 0; mf < 5; ++mf)                                                       \
            _Pragma("unroll")                                                                \
            for (int n = 0; n < 4; ++n)                                                      \
                acc[mf][n] = __builtin_amdgcn_mfma_f32_16x16x32_bf16(                        \
                    aS[(P) & 1][mf], bfr[n], acc[mf][n], 0, 0, 0);                           \
        if (t_ + 2 < 32) {                                                                   \
            _Pragma("unroll")                                                                \
            for (int mf = 0; mf < 5; ++mf)                                                   \
                aS[(P) & 1][mf] = *(const short8*)(aptr[mf] + (t_ + 2) * 32);                \
        }                                                                                    \
        asm volatile("s_waitcnt lgkmcnt(0)" ::: "memory");                                   \
        __builtin_amdgcn_s_barrier();                                                        \
    }

    for (int t8 = 0; t8 < 8; ++t8) {
        const int tb = t8 * 4;
        GSTEP(tb + 0, 0)
        GSTEP(tb + 1, 1)
        GSTEP(tb + 2, 2)
        GSTEP(tb + 3, 3)
    }
#undef GSTEP

    #pragma unroll
    for (int mf = 0; mf < 5; ++mf) {
        #pragma unroll
        for (int r = 0; r < 4; ++r) {
            const int rg = brow + wv * 80 + mf * 16 + lk * 4 + r;
            if (rg >= ne) continue;
            const int tok = token_of[roff + rg];
            const float g = gate_row[roff + rg];
            float* orow = out + (size_t)tok * HDIM;
            #pragma unroll
            for (int n = 0; n < 4; ++n) {
                const int d = d0 + n * 16 + lr;
                float v = g * acc[mf][n][r];
                if (ks == 0) v += g * b2[(size_t)e * HDIM + d];
                atomicAdd(orow + d, v);
            }
        }
    }
}

extern "C" void kernel_launch(void* const* d_in, const int* in_sizes, int n_in,
                              void* d_out, int out_size, void* d_ws, size_t ws_size,
                              hipStream_t stream) {
    const float* x      = (const float*)d_in[0];
    const float* norm_w = (const float*)d_in[1];
    const float* gate_w = (const float*)d_in[2];
    const float* gate_b = (const float*)d_in[3];
    const float* w1     = (const float*)d_in[4];
    const float* b1     = (const float*)d_in[5];
    const float* w2     = (const float*)d_in[6];
    const float* b2     = (const float*)d_in[7];
    float* out = (float*)d_out;

    char* ws = (char*)d_ws;
    size_t off = 0;
    unsigned short* t_bf = (unsigned short*)(ws + off); off += (size_t)MTOK * HDIM * 2;  // 4 MB
    unsigned short* actb = (unsigned short*)(ws + off); off += (size_t)NA * IDIM * 2;    // 16.8 MB
    int*   counts   = (int*)(ws + off);   off += 256;
    int*   idx_of   = (int*)(ws + off);   off += (size_t)NA * 4;
    int*   slot_of  = (int*)(ws + off);   off += (size_t)NA * 4;
    float* gate_mk  = (float*)(ws + off); off += (size_t)NA * 4;
    int*   token_of = (int*)(ws + off);   off += (size_t)NA * 4;
    float* gate_row = (float*)(ws + off); off += (size_t)NA * 4;

    (void)hipMemsetAsync(counts, 0, 256, stream);
    k_router<<<MTOK, 256, 0, stream>>>(x, norm_w, gate_w, gate_b, out, t_bf,
                                       counts, idx_of, slot_of, gate_mk);
    k_remap<<<NA / 256, 256, 0, stream>>>(idx_of, slot_of, gate_mk, counts,
                                          token_of, gate_row);
    k_gemm1<<<dim3(IDIM / 32, (MTOK + 319) / 320, NEXP), 256, 0, stream>>>(
        t_bf, w1, b1, counts, token_of, actb);
    k_gemm2<<<dim3((HDIM / 64) * 2, (MTOK + 319) / 320, NEXP), 256, 0, stream>>>(
        actb, w2, b2, counts, token_of, gate_row, out);
}

// Round 8
// 428.441 us; speedup vs baseline: 1.1291x; 1.1231x over previous
//
#include <hip/hip_runtime.h>
#include <hip/hip_bf16.h>

constexpr int MTOK = 1024;   // B*S
constexpr int HDIM = 2048;
constexpr int IDIM = 2048;
constexpr int NEXP = 16;
constexpr int TOPK = 4;
constexpr int NA   = MTOK * TOPK;   // 4096 assignments

#define ALPHA_C 1.702f
#define LIMIT_C 7.0f
#define RMS_EPS 1e-5f

using short8 = __attribute__((ext_vector_type(8))) short;
using f32x4  = __attribute__((ext_vector_type(4))) float;

__device__ __forceinline__ unsigned short f2bf(float f) {
    unsigned u = __builtin_bit_cast(unsigned, f);
    u += 0x7fffu + ((u >> 16) & 1u);     // round-to-nearest-even
    return (unsigned short)(u >> 16);
}

__device__ __forceinline__ unsigned pack2bf(float lo, float hi) {
    return (unsigned)f2bf(lo) | ((unsigned)f2bf(hi) << 16);
}

__device__ __forceinline__ short8 cvt8(const float4 a, const float4 b) {
    union { short8 s; unsigned u[4]; } r;
    r.u[0] = pack2bf(a.x, a.y);
    r.u[1] = pack2bf(a.z, a.w);
    r.u[2] = pack2bf(b.x, b.y);
    r.u[3] = pack2bf(b.z, b.w);
    return r.s;
}

// ---------------- RMSNorm + router + top-k ----------------
__global__ __launch_bounds__(256) void k_router(
    const float* __restrict__ x, const float* __restrict__ norm_w,
    const float* __restrict__ gate_w, const float* __restrict__ gate_b,
    unsigned short* __restrict__ t_bf,
    int* __restrict__ counts, int* __restrict__ idx_of,
    int* __restrict__ slot_of, float* __restrict__ gate_mk)
{
    __shared__ float t_lds[HDIM];
    __shared__ float red[4];
    __shared__ float logits[NEXP];

    const int m   = blockIdx.x;
    const int tid = threadIdx.x;
    const float* xr = x + (size_t)m * HDIM;

    float4 v0 = ((const float4*)xr)[tid * 2];
    float4 v1 = ((const float4*)xr)[tid * 2 + 1];
    float ss = v0.x*v0.x + v0.y*v0.y + v0.z*v0.z + v0.w*v0.w
             + v1.x*v1.x + v1.y*v1.y + v1.z*v1.z + v1.w*v1.w;
    #pragma unroll
    for (int off = 32; off > 0; off >>= 1) ss += __shfl_down(ss, off);
    if ((tid & 63) == 0) red[tid >> 6] = ss;
    __syncthreads();
    float tot = red[0] + red[1] + red[2] + red[3];
    float scale = rsqrtf(tot / (float)HDIM + RMS_EPS);

    float4 n0 = ((const float4*)norm_w)[tid * 2];
    float4 n1 = ((const float4*)norm_w)[tid * 2 + 1];
    float t[8];
    t[0]=v0.x*scale*n0.x; t[1]=v0.y*scale*n0.y; t[2]=v0.z*scale*n0.z; t[3]=v0.w*scale*n0.w;
    t[4]=v1.x*scale*n1.x; t[5]=v1.y*scale*n1.y; t[6]=v1.z*scale*n1.z; t[7]=v1.w*scale*n1.w;
    short8 pk;
    #pragma unroll
    for (int j = 0; j < 8; ++j) {
        t_lds[tid * 8 + j] = t[j];
        pk[j] = (short)f2bf(t[j]);
    }
    *(short8*)(t_bf + (size_t)m * HDIM + tid * 8) = pk;
    __syncthreads();

    const int e = tid >> 4, j = tid & 15;
    const float4* gw4 = (const float4*)(gate_w + (size_t)e * HDIM);
    const float4* tl4 = (const float4*)t_lds;
    float part = 0.f;
    for (int h4 = j; h4 < HDIM / 4; h4 += 16) {
        float4 g = gw4[h4], tv = tl4[h4];
        part += g.x*tv.x + g.y*tv.y + g.z*tv.z + g.w*tv.w;
    }
    #pragma unroll
    for (int off = 8; off > 0; off >>= 1) part += __shfl_xor(part, off);
    if (j == 0) logits[e] = part + gate_b[e];
    __syncthreads();

    if (tid == 0) {
        float lv[NEXP];
        #pragma unroll
        for (int q = 0; q < NEXP; ++q) lv[q] = logits[q];
        int   sel[TOPK];
        float sv[TOPK];
        #pragma unroll
        for (int k = 0; k < TOPK; ++k) {
            float best = -1e30f; int bi = 0;
            for (int q = 0; q < NEXP; ++q)
                if (lv[q] > best) { best = lv[q]; bi = q; }
            sel[k] = bi; sv[k] = best; lv[bi] = -1e30f;
        }
        float mx = sv[0], s = 0.f, g[TOPK];
        #pragma unroll
        for (int k = 0; k < TOPK; ++k) { g[k] = __expf(sv[k] - mx); s += g[k]; }
        float inv = 1.f / s;
        #pragma unroll
        for (int k = 0; k < TOPK; ++k) {
            int a = m * TOPK + k;
            int slot = atomicAdd(&counts[sel[k]], 1);
            idx_of[a]  = sel[k];
            slot_of[a] = slot;
            gate_mk[a] = g[k] * inv;
        }
    }
}

// ---------------- scatter tokens into compact per-expert rows ----------------
__global__ void k_remap(const int* __restrict__ idx_of, const int* __restrict__ slot_of,
                        const int* __restrict__ counts,
                        int* __restrict__ token_of, int* __restrict__ rowidx)
{
    int a = blockIdx.x * blockDim.x + threadIdx.x;
    if (a >= NA) return;
    int e = idx_of[a];
    int off = 0;
    for (int q = 0; q < NEXP; ++q) off += (q < e) ? counts[q] : 0;
    int r = off + slot_of[a];
    token_of[r] = a >> 2;
    rowidx[a]   = r;
}

// ---------------- GEMM1 + bias + clamped SwiGLU -> act (bf16) ----------------
// BM=320, BK=64, 32 K-steps. 4 waves; wave wv owns rows [wv*80,+80) x 64 cols.
// A: direct global->reg from L2-hot t_bf (reload right after last use).
// B: 4 named fp32 reg sets (tile x -> set x&3); issue at t for tile t+3,
// publish (cvt->LDS) at t+2 -> 2-step (~1600cy) latency budget. Per-wave B
// in flight ~8KB. lgkmcnt-only barriers; vmem never drained in-loop.
__global__ __launch_bounds__(256) void k_gemm1(
    const unsigned short* __restrict__ t_bf,
    const float* __restrict__ w1, const float* __restrict__ b1,
    const int* __restrict__ counts, const int* __restrict__ token_of,
    unsigned short* __restrict__ act)
{
    __shared__ unsigned char lB[2][2][5120];   // [buf][kk][64 cols x 80B]

    const int e = blockIdx.z;
    int ne = 0, roff = 0;
    #pragma unroll
    for (int q = 0; q < NEXP; ++q) {
        int cq = counts[q];
        roff += (q < e) ? cq : 0;
        ne    = (q == e) ? cq : ne;
    }
    const int brow = blockIdx.y * 320;
    if (brow >= ne) return;
    const int i0 = blockIdx.x * 32;
    const int tid = threadIdx.x;

    const int wv = tid >> 6, ln = tid & 63;
    const int lr = ln & 15, lk = ln >> 4;
    const int br = tid >> 2, bp = tid & 3;   // B staging: col br, 16-float chunk bp

    const unsigned short* aptr[5];
    #pragma unroll
    for (int mf = 0; mf < 5; ++mf) {
        int rg = brow + wv * 80 + mf * 16 + lr;
        int tok = token_of[roff + (rg < ne ? rg : 0)];
        aptr[mf] = t_bf + (size_t)tok * HDIM + lk * 8;
    }
    const int o = (br < 32) ? (2 * (i0 + br)) : (2 * (i0 + br - 32) + 1);
    const float* bsrc = w1 + ((size_t)e * (2 * IDIM) + o) * HDIM + bp * 16;

    float4 bS0[4], bS1[4], bS2[4], bS3[4];
    short8 aA0[5], aA1[5];
    f32x4  acc[5][4] = {};

    constexpr int NT = 32;   // HDIM / 64

    // prologue: tile0 sync -> LDS buf0; issue tiles 1,2,3; A for step 0
    {
        float4 p0 = *(const float4*)(bsrc);
        float4 p1 = *(const float4*)(bsrc + 4);
        float4 p2 = *(const float4*)(bsrc + 8);
        float4 p3 = *(const float4*)(bsrc + 12);
        *(short8*)(&lB[0][bp >> 1][br * 80 + (bp & 1) * 32])      = cvt8(p0, p1);
        *(short8*)(&lB[0][bp >> 1][br * 80 + (bp & 1) * 32 + 16]) = cvt8(p2, p3);
    }
    #pragma unroll
    for (int j = 0; j < 4; ++j) {
        bS1[j] = *(const float4*)(bsrc + 64  + j * 4);
        bS2[j] = *(const float4*)(bsrc + 128 + j * 4);
        bS3[j] = *(const float4*)(bsrc + 192 + j * 4);
    }
    #pragma unroll
    for (int mf = 0; mf < 5; ++mf) {
        aA0[mf] = *(const short8*)(aptr[mf]);
        aA1[mf] = *(const short8*)(aptr[mf] + 32);
    }
    asm volatile("s_waitcnt lgkmcnt(0)" ::: "memory");
    __builtin_amdgcn_s_barrier();

#define GSTEP(T_, SPUB, SISS)                                                            \
    {                                                                                    \
        const int t_ = (T_);                                                             \
        const int c_ = t_ & 1;                                                           \
        if (t_ + 1 < NT) {  /* publish tile t+1 */                                       \
            *(short8*)(&lB[c_ ^ 1][bp >> 1][br * 80 + (bp & 1) * 32])      =             \
                cvt8(SPUB[0], SPUB[1]);                                                  \
            *(short8*)(&lB[c_ ^ 1][bp >> 1][br * 80 + (bp & 1) * 32 + 16]) =             \
                cvt8(SPUB[2], SPUB[3]);                                                  \
        }                                                                                \
        if (t_ + 3 < NT) {  /* issue tile t+3 */                                         \
            _Pragma("unroll")                                                            \
            for (int j = 0; j < 4; ++j)                                                  \
                SISS[j] = *(const float4*)(bsrc + (t_ + 3) * 64 + j * 4);                \
        }                                                                                \
        short8 bfr[4];                                                                   \
        _Pragma("unroll")                                                                \
        for (int n = 0; n < 4; ++n)                                                      \
            bfr[n] = *(const short8*)(&lB[c_][0][(n * 16 + lr) * 80 + lk * 16]);         \
        _Pragma("unroll")                                                                \
        for (int mf = 0; mf < 5; ++mf)                                                   \
            _Pragma("unroll")                                                            \
            for (int n = 0; n < 4; ++n)                                                  \
                acc[mf][n] = __builtin_amdgcn_mfma_f32_16x16x32_bf16(                    \
                    aA0[mf], bfr[n], acc[mf][n], 0, 0, 0);                               \
        _Pragma("unroll")                                                                \
        for (int n = 0; n < 4; ++n)                                                      \
            bfr[n] = *(const short8*)(&lB[c_][1][(n * 16 + lr) * 80 + lk * 16]);         \
        _Pragma("unroll")                                                                \
        for (int mf = 0; mf < 5; ++mf)                                                   \
            _Pragma("unroll")                                                            \
            for (int n = 0; n < 4; ++n)                                                  \
                acc[mf][n] = __builtin_amdgcn_mfma_f32_16x16x32_bf16(                    \
                    aA1[mf], bfr[n], acc[mf][n], 0, 0, 0);                               \
        if (t_ + 1 < NT) {  /* reload A for step t+1 (L2-hot) */                         \
            _Pragma("unroll")                                                            \
            for (int mf = 0; mf < 5; ++mf) {                                             \
                aA0[mf] = *(const short8*)(aptr[mf] + (t_ + 1) * 64);                    \
                aA1[mf] = *(const short8*)(aptr[mf] + (t_ + 1) * 64 + 32);               \
            }                                                                            \
        }                                                                                \
        asm volatile("s_waitcnt lgkmcnt(0)" ::: "memory");                               \
        __builtin_amdgcn_s_barrier();                                                    \
    }

    for (int t8 = 0; t8 < NT / 4; ++t8) {
        const int tb = t8 * 4;
        GSTEP(tb + 0, bS1, bS3)
        GSTEP(tb + 1, bS2, bS0)
        GSTEP(tb + 2, bS3, bS1)
        GSTEP(tb + 3, bS0, bS2)
    }
#undef GSTEP

    #pragma unroll
    for (int n = 0; n < 2; ++n) {
        const int i = i0 + n * 16 + lr;
        const float ba = b1[(size_t)e * (2 * IDIM) + 2 * i];
        const float bb = b1[(size_t)e * (2 * IDIM) + 2 * i + 1];
        #pragma unroll
        for (int mf = 0; mf < 5; ++mf) {
            #pragma unroll
            for (int r = 0; r < 4; ++r) {
                const int rg = brow + wv * 80 + mf * 16 + lk * 4 + r;
                if (rg < ne) {
                    float ha = acc[mf][n][r] + ba;
                    float hb = acc[mf][n + 2][r] + bb;
                    float a = fminf(ha, LIMIT_C);
                    float b = fminf(fmaxf(hb, -LIMIT_C), LIMIT_C);
                    float s = 1.f / (1.f + __expf(-ALPHA_C * a));
                    act[(size_t)(roff + rg) * IDIM + i] = f2bf(a * s * (b + 1.f));
                }
            }
        }
    }
}

// ---------------- GEMM2 + bias -> ybuf (bf16, un-gated) ----------------
__global__ __launch_bounds__(256) void k_gemm2(
    const unsigned short* __restrict__ act,
    const float* __restrict__ w2, const float* __restrict__ b2,
    const int* __restrict__ counts, const int* __restrict__ token_of,
    unsigned short* __restrict__ ybuf)
{
    __shared__ unsigned char lB[2][2][5120];

    const int e = blockIdx.z;
    int ne = 0, roff = 0;
    #pragma unroll
    for (int q = 0; q < NEXP; ++q) {
        int cq = counts[q];
        roff += (q < e) ? cq : 0;
        ne    = (q == e) ? cq : ne;
    }
    const int brow = blockIdx.y * 320;
    if (brow >= ne) return;
    const int d0 = blockIdx.x * 64;
    const int tid = threadIdx.x;

    const int wv = tid >> 6, ln = tid & 63;
    const int lr = ln & 15, lk = ln >> 4;
    const int br = tid >> 2, bp = tid & 3;

    const unsigned short* aptr[5];
    #pragma unroll
    for (int mf = 0; mf < 5; ++mf) {
        int rg = brow + wv * 80 + mf * 16 + lr;
        int rc = (rg < ne) ? rg : 0;
        aptr[mf] = act + (size_t)(roff + rc) * IDIM + lk * 8;
    }
    const float* bsrc = w2 + ((size_t)e * HDIM + d0 + br) * IDIM + bp * 16;

    float4 bS0[4], bS1[4], bS2[4], bS3[4];
    short8 aA0[5], aA1[5];
    f32x4  acc[5][4] = {};

    constexpr int NT = 32;   // IDIM / 64

    {
        float4 p0 = *(const float4*)(bsrc);
        float4 p1 = *(const float4*)(bsrc + 4);
        float4 p2 = *(const float4*)(bsrc + 8);
        float4 p3 = *(const float4*)(bsrc + 12);
        *(short8*)(&lB[0][bp >> 1][br * 80 + (bp & 1) * 32])      = cvt8(p0, p1);
        *(short8*)(&lB[0][bp >> 1][br * 80 + (bp & 1) * 32 + 16]) = cvt8(p2, p3);
    }
    #pragma unroll
    for (int j = 0; j < 4; ++j) {
        bS1[j] = *(const float4*)(bsrc + 64  + j * 4);
        bS2[j] = *(const float4*)(bsrc + 128 + j * 4);
        bS3[j] = *(const float4*)(bsrc + 192 + j * 4);
    }
    #pragma unroll
    for (int mf = 0; mf < 5; ++mf) {
        aA0[mf] = *(const short8*)(aptr[mf]);
        aA1[mf] = *(const short8*)(aptr[mf] + 32);
    }
    asm volatile("s_waitcnt lgkmcnt(0)" ::: "memory");
    __builtin_amdgcn_s_barrier();

#define GSTEP(T_, SPUB, SISS)                                                            \
    {                                                                                    \
        const int t_ = (T_);                                                             \
        const int c_ = t_ & 1;                                                           \
        if (t_ + 1 < NT) {                                                               \
            *(short8*)(&lB[c_ ^ 1][bp >> 1][br * 80 + (bp & 1) * 32])      =             \
                cvt8(SPUB[0], SPUB[1]);                                                  \
            *(short8*)(&lB[c_ ^ 1][bp >> 1][br * 80 + (bp & 1) * 32 + 16]) =             \
                cvt8(SPUB[2], SPUB[3]);                                                  \
        }                                                                                \
        if (t_ + 3 < NT) {                                                               \
            _Pragma("unroll")                                                            \
            for (int j = 0; j < 4; ++j)                                                  \
                SISS[j] = *(const float4*)(bsrc + (t_ + 3) * 64 + j * 4);                \
        }                                                                                \
        short8 bfr[4];                                                                   \
        _Pragma("unroll")                                                                \
        for (int n = 0; n < 4; ++n)                                                      \
            bfr[n] = *(const short8*)(&lB[c_][0][(n * 16 + lr) * 80 + lk * 16]);         \
        _Pragma("unroll")                                                                \
        for (int mf = 0; mf < 5; ++mf)                                                   \
            _Pragma("unroll")                                                            \
            for (int n = 0; n < 4; ++n)                                                  \
                acc[mf][n] = __builtin_amdgcn_mfma_f32_16x16x32_bf16(                    \
                    aA0[mf], bfr[n], acc[mf][n], 0, 0, 0);                               \
        _Pragma("unroll")                                                                \
        for (int n = 0; n < 4; ++n)                                                      \
            bfr[n] = *(const short8*)(&lB[c_][1][(n * 16 + lr) * 80 + lk * 16]);         \
        _Pragma("unroll")                                                                \
        for (int mf = 0; mf < 5; ++mf)                                                   \
            _Pragma("unroll")                                                            \
            for (int n = 0; n < 4; ++n)                                                  \
                acc[mf][n] = __builtin_amdgcn_mfma_f32_16x16x32_bf16(                    \
                    aA1[mf], bfr[n], acc[mf][n], 0, 0, 0);                               \
        if (t_ + 1 < NT) {                                                               \
            _Pragma("unroll")                                                            \
            for (int mf = 0; mf < 5; ++mf) {                                             \
                aA0[mf] = *(const short8*)(aptr[mf] + (t_ + 1) * 64);                    \
                aA1[mf] = *(const short8*)(aptr[mf] + (t_ + 1) * 64 + 32);               \
            }                                                                            \
        }                                                                                \
        asm volatile("s_waitcnt lgkmcnt(0)" ::: "memory");                               \
        __builtin_amdgcn_s_barrier();                                                    \
    }

    for (int t8 = 0; t8 < NT / 4; ++t8) {
        const int tb = t8 * 4;
        GSTEP(tb + 0, bS1, bS3)
        GSTEP(tb + 1, bS2, bS0)
        GSTEP(tb + 2, bS3, bS1)
        GSTEP(tb + 3, bS0, bS2)
    }
#undef GSTEP

    #pragma unroll
    for (int mf = 0; mf < 5; ++mf) {
        #pragma unroll
        for (int r = 0; r < 4; ++r) {
            const int rg = brow + wv * 80 + mf * 16 + lk * 4 + r;
            if (rg >= ne) continue;
            unsigned short* yrow = ybuf + (size_t)(roff + rg) * HDIM;
            #pragma unroll
            for (int n = 0; n < 4; ++n) {
                const int d = d0 + n * 16 + lr;
                yrow[d] = f2bf(acc[mf][n][r] + b2[(size_t)e * HDIM + d]);
            }
        }
    }
}

// ---------------- combine: out = x + sum_k gate_k * ybuf[row_k] ----------------
__global__ __launch_bounds__(256) void k_comb(
    const float* __restrict__ x, const unsigned short* __restrict__ ybuf,
    const int* __restrict__ rowidx, const float* __restrict__ gate_mk,
    float* __restrict__ out)
{
    __shared__ int   rws[TOPK];
    __shared__ float gws[TOPK];
    const int m = blockIdx.x;
    const int tid = threadIdx.x;
    if (tid < TOPK) {
        rws[tid] = rowidx[m * TOPK + tid];
        gws[tid] = gate_mk[m * TOPK + tid];
    }
    __syncthreads();
    const int d = tid * 8;
    float4 o0 = ((const float4*)(x + (size_t)m * HDIM + d))[0];
    float4 o1 = ((const float4*)(x + (size_t)m * HDIM + d))[1];
    #pragma unroll
    for (int k = 0; k < TOPK; ++k) {
        const float g = gws[k];
        short8 y = *(const short8*)(ybuf + (size_t)rws[k] * HDIM + d);
        float yv[8];
        #pragma unroll
        for (int j = 0; j < 8; ++j) {
            unsigned u = ((unsigned)(unsigned short)y[j]) << 16;
            yv[j] = __builtin_bit_cast(float, u);
        }
        o0.x += g * yv[0]; o0.y += g * yv[1]; o0.z += g * yv[2]; o0.w += g * yv[3];
        o1.x += g * yv[4]; o1.y += g * yv[5]; o1.z += g * yv[6]; o1.w += g * yv[7];
    }
    ((float4*)(out + (size_t)m * HDIM + d))[0] = o0;
    ((float4*)(out + (size_t)m * HDIM + d))[1] = o1;
}

extern "C" void kernel_launch(void* const* d_in, const int* in_sizes, int n_in,
                              void* d_out, int out_size, void* d_ws, size_t ws_size,
                              hipStream_t stream) {
    const float* x      = (const float*)d_in[0];
    const float* norm_w = (const float*)d_in[1];
    const float* gate_w = (const float*)d_in[2];
    const float* gate_b = (const float*)d_in[3];
    const float* w1     = (const float*)d_in[4];
    const float* b1     = (const float*)d_in[5];
    const float* w2     = (const float*)d_in[6];
    const float* b2     = (const float*)d_in[7];
    float* out = (float*)d_out;

    char* ws = (char*)d_ws;
    size_t off = 0;
    unsigned short* t_bf = (unsigned short*)(ws + off); off += (size_t)MTOK * HDIM * 2;  // 4 MB
    unsigned short* actb = (unsigned short*)(ws + off); off += (size_t)NA * IDIM * 2;    // 16.8 MB
    unsigned short* ybuf = (unsigned short*)(ws + off); off += (size_t)NA * HDIM * 2;    // 16.8 MB
    int*   counts   = (int*)(ws + off);   off += 256;
    int*   idx_of   = (int*)(ws + off);   off += (size_t)NA * 4;
    int*   slot_of  = (int*)(ws + off);   off += (size_t)NA * 4;
    float* gate_mk  = (float*)(ws + off); off += (size_t)NA * 4;
    int*   token_of = (int*)(ws + off);   off += (size_t)NA * 4;
    int*   rowidx   = (int*)(ws + off);   off += (size_t)NA * 4;

    (void)hipMemsetAsync(counts, 0, 256, stream);
    k_router<<<MTOK, 256, 0, stream>>>(x, norm_w, gate_w, gate_b, t_bf,
                                       counts, idx_of, slot_of, gate_mk);
    k_remap<<<NA / 256, 256, 0, stream>>>(idx_of, slot_of, counts,
                                          token_of, rowidx);
    k_gemm1<<<dim3(IDIM / 32, (MTOK + 319) / 320, NEXP), 256, 0, stream>>>(
        t_bf, w1, b1, counts, token_of, actb);
    k_gemm2<<<dim3(HDIM / 64, (MTOK + 319) / 320, NEXP), 256, 0, stream>>>(
        actb, w2, b2, counts, token_of, ybuf);
    k_comb<<<MTOK, 256, 0, stream>>>(x, ybuf, rowidx, gate_mk, out);
}